// Round 8
// baseline (1268.786 us; speedup 1.0000x reference)
//
#include <hip/hip_runtime.h>
#include <math.h>

#define B 4
#define T 512
#define D 256
#define H 1024
#define NH 8
#define V 32000
#define BT (B*T)
#define LE 2
#define LD 2
#define DIM 1024  // expanded width = 4*D

typedef __attribute__((ext_vector_type(8))) short s16x8;
typedef __attribute__((ext_vector_type(4))) float f32x4;
typedef __attribute__((address_space(3))) void lds_void;
typedef const __attribute__((address_space(1))) void g_void;

__device__ __forceinline__ ushort f2bf(float x) {
  uint u = __float_as_uint(x);
  return (ushort)((u + 0x7fffu + ((u >> 16) & 1u)) >> 16);
}
__device__ __forceinline__ float bf2f(ushort u) {
  return __uint_as_float(((uint)u) << 16);
}

// ---------------------------------------------------------------------------
// embed + rope fused for BOTH src and tgt: grid 2*BT
__global__ __launch_bounds__(256) void embed_rope_kernel(
    const int* __restrict__ src, const int* __restrict__ tgt,
    const float* __restrict__ emb,
    float* __restrict__ osrc, ushort* __restrict__ osrcbf,
    float* __restrict__ otgt, ushort* __restrict__ otgtbf) {
  int g = blockIdx.x;
  int isTgt = g >= BT;
  int bt = isTgt ? g - BT : g;
  int d  = threadIdx.x;
  int id = isTgt ? tgt[bt] : src[bt];
  float* out = isTgt ? otgt : osrc;
  ushort* outbf = isTgt ? otgtbf : osrcbf;
  int t  = bt % T;
  size_t VD = (size_t)V * D;
  float scale = powf(10000.f, -(float)d / (float)D);
  float r = emb[(size_t)id * D + d];
  float i = emb[VD + (size_t)id * D + d] * scale;
  float j = emb[2 * VD + (size_t)id * D + d] * scale;
  float k = emb[3 * VD + (size_t)id * D + d] * scale;
  float n = sqrtf(r * r + i * i + j * j + k * k + 1e-6f);
  float ang;
  if (d < D / 2) {
    float inv = powf(10000.f, -(float)(2 * d) / (float)D);
    ang = sinf((float)t * inv);
  } else {
    float inv = powf(10000.f, -(float)(2 * (d - D / 2)) / (float)D);
    ang = cosf((float)t * inv);
  }
  float s = ang / n;
  size_t base = (size_t)bt * DIM + d * 4;
  float4 q = make_float4(r * s, i * s, j * s, k * s);
  *(float4*)(out + base) = q;
  *(ushort4*)(outbf + base) = make_ushort4(f2bf(q.x), f2bf(q.y), f2bf(q.z), f2bf(q.w));
}

// ---------------------------------------------------------------------------
// ONE launch: expand all quaternion weights to bf16 B^T form + fc_W convert
#define A_CNT  1572864
#define F_CNT  2097152
#define FC_CNT 2048000
#define MEGA_TOT (A_CNT + F_CNT + FC_CNT)
#define WSTEP  1048576   // DIM*DIM elems
#define FFW    4194304   // 4H*DIM elems

__device__ __forceinline__ void qexpand_write(
    const float* __restrict__ src, ushort* __restrict__ dst,
    int o, int d, int Din, int P) {
  float w0 = src[(size_t)o * Din + d];
  float w1 = src[P + (size_t)o * Din + d];
  float w2 = src[2 * (size_t)P + (size_t)o * Din + d];
  float w3 = src[3 * (size_t)P + (size_t)o * Din + d];
  int K4 = Din * 4;
  size_t rbase = (size_t)(o * 4) * K4 + d * 4;
  *(ushort4*)(dst + rbase)          = make_ushort4(f2bf(w0), f2bf(-w1), f2bf(-w2), f2bf(-w3));
  *(ushort4*)(dst + rbase + K4)     = make_ushort4(f2bf(w1), f2bf(w0),  f2bf(w3),  f2bf(-w2));
  *(ushort4*)(dst + rbase + 2 * K4) = make_ushort4(f2bf(w2), f2bf(-w3), f2bf(w0),  f2bf(w1));
  *(ushort4*)(dst + rbase + 3 * K4) = make_ushort4(f2bf(w3), f2bf(w2),  f2bf(-w1), f2bf(w0));
}

__global__ __launch_bounds__(256) void mega_expand_kernel(
    const float* __restrict__ encA, const float* __restrict__ decSA,
    const float* __restrict__ decCA,
    const float* __restrict__ eW1, const float* __restrict__ eW2,
    const float* __restrict__ dW1, const float* __restrict__ dW2,
    const float* __restrict__ fcW,
    ushort* __restrict__ WA, ushort* __restrict__ WF, ushort* __restrict__ Wfc) {
  int gid = blockIdx.x * 256 + threadIdx.x;
  if (gid < A_CNT) {
    int u = gid >> 18;
    int p = (gid >> 16) & 3;
    int rem = gid & 65535;
    int o = rem >> 8, d = rem & 255;
    const float* base = (u < 2) ? encA + (size_t)u * 1048576
                      : (u < 4) ? decSA + (size_t)(u - 2) * 1048576
                                : decCA + (size_t)(u - 4) * 1048576;
    qexpand_write(base + (size_t)p * 262144,
                  WA + ((size_t)u * 4 + p) * WSTEP, o, d, 256, 65536);
  } else if (gid < A_CNT + F_CNT) {
    int idx = gid - A_CNT;
    int layer = idx >> 19;
    int w12 = (idx >> 18) & 1;
    int rem = idx & 262143;
    const float* w1b = (layer < 2) ? eW1 + (size_t)layer * 1048576
                                   : dW1 + (size_t)(layer - 2) * 1048576;
    const float* w2b = (layer < 2) ? eW2 + (size_t)layer * 1048576
                                   : dW2 + (size_t)(layer - 2) * 1048576;
    ushort* dst = WF + (size_t)layer * 2 * FFW + (size_t)w12 * FFW;
    if (w12 == 0) {
      int o = rem >> 8, d = rem & 255;
      qexpand_write(w1b, dst, o, d, 256, 262144);
    } else {
      int o = rem >> 10, d = rem & 1023;
      qexpand_write(w2b, dst, o, d, 1024, 262144);
    }
  } else {
    int idx = gid - A_CNT - F_CNT;
    if (idx < FC_CNT) {
      float4 v = ((const float4*)fcW)[idx];
      ((ushort4*)Wfc)[idx] = make_ushort4(f2bf(v.x), f2bf(v.y), f2bf(v.z), f2bf(v.w));
    }
  }
}

// ---------------------------------------------------------------------------
// C[M,N] = A[M,K]bf16 * Bt[N,K]bf16^T (+bias).
// BK=32, 3-buffer depth-2 pipeline with COUNTED vmcnt + raw s_barrier (T3/T4):
//   stage(0); stage(1);
//   loop t: { waitcnt vmcnt(LPT); s_barrier; stage(t+2); compute(t); }
// Every wave counts its own vmcnt before the barrier -> cross-wave LDS safe.
// m-fastest XCD-chunked block order: per-XCD set = few B panels + A (fits L2).
// OMODE 0: f32+bias. OMODE 3: QKV epilogue. OMODE 4: +resid+qnorm (+real).
// OMODE 5: +modrelu -> bf16.
template <int OMODE, int TM>
__global__ __launch_bounds__(256) void gemm_bf16_kernel(
    const ushort* __restrict__ A, const ushort* __restrict__ Bt,
    const float* __restrict__ bias, void* __restrict__ Cv, int N, int K,
    ushort* __restrict__ qo, ushort* __restrict__ ko, ushort* __restrict__ vo,
    int colbase,
    float* __restrict__ xres, ushort* __restrict__ xbf,
    const float* __restrict__ gg, const float* __restrict__ bb,
    const float* __restrict__ modb, ushort* __restrict__ realout) {
  __shared__ ushort As[3][TM * 32];
  __shared__ ushort Bs[3][128 * 32];
  const int tid = threadIdx.x;
  const int w = tid >> 6, l = tid & 63;
  // ---- XCD-aware bijective remap, m varies fastest within an XCD chunk
  const int nbx = N >> 7;
  const int nwg = gridDim.x;
  const int nby = nwg / nbx;
  const int qq = nwg >> 3, rr = nwg & 7;
  const int xcd = blockIdx.x & 7, pos = blockIdx.x >> 3;
  const int wg = (xcd < rr ? xcd * (qq + 1) : rr * (qq + 1) + (xcd - rr) * qq) + pos;
  const int m0 = (wg % nby) * TM, n0 = (wg / nby) * 128;
  const int lr = l & 15, lg = l >> 4;
  constexpr int NR = (TM == 128) ? 4 : 2;
  constexpr int LPT = TM / 64 + 2;   // global_load_lds per thread per stage
  const int wm = (TM == 128) ? (w >> 1) : 0;
  const int wn = (TM == 128) ? (w & 1) : w;
  const int wcol = wn * (NR * 16);
  f32x4 acc[4][NR] = {};
  const int NT = K >> 5;

  auto stage = [&](int t, int buf) {
    int k0 = (t < NT ? t : NT - 1) << 5;
#pragma unroll
    for (int s = 0; s < TM / 64; ++s) {
      int fb = (w * (TM / 64) + s) * 1024;
      int f = fb + l * 16;
      int row = f >> 6, cb = (f & 63) >> 1;
      __builtin_amdgcn_global_load_lds(
          (g_void*)(A + (size_t)(m0 + row) * K + k0 + cb),
          (lds_void*)((char*)&As[buf][0] + fb), 16, 0, 0);
    }
#pragma unroll
    for (int s = 0; s < 2; ++s) {
      int fb = (w * 2 + s) * 1024;
      int f = fb + l * 16;
      int row = f >> 6, cb = (f & 63) >> 1;
      __builtin_amdgcn_global_load_lds(
          (g_void*)(Bt + (size_t)(n0 + row) * K + k0 + cb),
          (lds_void*)((char*)&Bs[buf][0] + fb), 16, 0, 0);
    }
  };

  stage(0, 0);
  stage(1, 1);
  for (int t = 0; t < NT; ++t) {
    const int cur = t % 3;
    const int nxt = (t + 2) % 3;
    // stage(t) complete in THIS wave (only stage(t+1)'s LPT loads may remain)
    if constexpr (TM == 128)
      asm volatile("s_waitcnt vmcnt(4)" ::: "memory");
    else
      asm volatile("s_waitcnt vmcnt(3)" ::: "memory");
    __builtin_amdgcn_s_barrier();   // all waves staged t; all done reading buf nxt
    stage(t + 2, nxt);              // issue early: 2 iterations of cover
    s16x8 af[4], bfr[NR];
#pragma unroll
    for (int mi = 0; mi < 4; ++mi)
      af[mi] = *(const s16x8*)(&As[cur][0] + (wm * 64 + mi * 16 + lr) * 32 + lg * 8);
#pragma unroll
    for (int ni = 0; ni < NR; ++ni)
      bfr[ni] = *(const s16x8*)(&Bs[cur][0] + (wcol + ni * 16 + lr) * 32 + lg * 8);
    __builtin_amdgcn_s_setprio(1);
#pragma unroll
    for (int mi = 0; mi < 4; ++mi)
#pragma unroll
      for (int ni = 0; ni < NR; ++ni)
        acc[mi][ni] = __builtin_amdgcn_mfma_f32_16x16x32_bf16(af[mi], bfr[ni], acc[mi][ni], 0, 0, 0);
    __builtin_amdgcn_s_setprio(0);
  }
  asm volatile("s_waitcnt vmcnt(0)" ::: "memory");  // drain dead prefetches (LDS reuse safety)

#pragma unroll
  for (int mi = 0; mi < 4; ++mi) {
#pragma unroll
    for (int ni = 0; ni < NR; ++ni) {
      int row = m0 + wm * 64 + mi * 16 + lg * 4;
      int col = n0 + wcol + ni * 16 + lr;
      f32x4 v = acc[mi][ni];
      if constexpr (OMODE == 0) {
        float bv = bias ? bias[col] : 0.f;
        float* C = (float*)Cv;
#pragma unroll
        for (int r = 0; r < 4; ++r)
          C[(size_t)(row + r) * N + col] = v[r] + bv;
      } else if constexpr (OMODE == 3) {
        int gc = colbase + col;
        float bv = bias[gc];
        if (gc < 2048) {
          ushort* dst = (gc < DIM) ? qo : ko;
          int c = gc & (DIM - 1);
#pragma unroll
          for (int r = 0; r < 4; ++r)
            dst[(size_t)(row + r) * DIM + c] = f2bf(v[r] + bv);
        } else {
          int c = gc - 2048;
          ushort4 o4 = make_ushort4(f2bf(v[0] + bv), f2bf(v[1] + bv),
                                    f2bf(v[2] + bv), f2bf(v[3] + bv));
          *(ushort4*)&vo[((size_t)((row >> 9) << 10) + c) * T + (row & 511)] = o4;
        }
      } else if constexpr (OMODE == 4) {
        float bv = bias[col];
        float gv = gg[col], bev = bb[col];
#pragma unroll
        for (int r = 0; r < 4; ++r) {
          float val = v[r] + bv + xres[(size_t)(row + r) * DIM + col];
          float sq = val * val;
          sq += __shfl_xor(sq, 1);
          sq += __shfl_xor(sq, 2);
          float invn = rsqrtf(sq + 1e-6f);
          float res = gv * (val * invn) + bev;
          xres[(size_t)(row + r) * DIM + col] = res;
          xbf[(size_t)(row + r) * DIM + col] = f2bf(res);
          if (realout) {
            float rsq = res * res;
            rsq += __shfl_xor(rsq, 1);
            rsq += __shfl_xor(rsq, 2);
            if ((col & 3) == 0)
              realout[(size_t)(row + r) * D + (col >> 2)] = f2bf(sqrtf(rsq));
          }
        }
      } else {  // OMODE 5: modrelu
        float bv = bias[col];
        float mb = modb[col >> 2];
        ushort* C = (ushort*)Cv;
#pragma unroll
        for (int r = 0; r < 4; ++r) {
          float val = v[r] + bv;
          float sq = val * val;
          sq += __shfl_xor(sq, 1);
          sq += __shfl_xor(sq, 2);
          float norm = sqrtf(sq);
          float scale = fmaxf(norm + mb, 0.f) / (norm + 1e-6f);
          C[(size_t)(row + r) * N + col] = f2bf(val * scale);
        }
      }
    }
  }
}

// ---------------------------------------------------------------------------
// fused flash attention, head-dim 128. grid (T/64, NH, B), 4 waves x 16 q-rows.
// K/V tiles staged ONCE per block into XOR-swizzled LDS (double-buffered),
// shared by all 4 waves. Causal kend is wave-uniform: (blockIdx.x+1)*64.
__global__ __launch_bounds__(256) void fused_attn_kernel(
    const ushort* __restrict__ qb, const ushort* __restrict__ kb,
    const ushort* __restrict__ vT, ushort* __restrict__ outA, int causal) {
  __shared__ ushort Ks[2][64 * 128];   // 16KB each: 64 kv-rows x 128 d
  __shared__ ushort Vs[2][128 * 64];   // 16KB each: 128 d x 64 kv
  __shared__ ushort Pst[4][1024];
  const int tid = threadIdx.x;
  const int wq = tid >> 6, l = tid & 63;
  const int lr = l & 15, lg = l >> 4;
  const int h = blockIdx.y, b = blockIdx.z;
  const int q0 = blockIdx.x * 64 + wq * 16;
  const size_t bT = (size_t)b * T;
  const int hc = h * 128;
  const size_t vrow0 = (size_t)(b * NH + h) * 128;
  s16x8 qf[4];
#pragma unroll
  for (int ks = 0; ks < 4; ++ks)
    qf[ks] = *(const s16x8*)(qb + (bT + q0 + lr) * DIM + hc + ks * 32 + lg * 8);
  f32x4 O[8] = {};
  float m[4] = {-3e38f, -3e38f, -3e38f, -3e38f};
  float lac[4] = {0.f, 0.f, 0.f, 0.f};
  const int kend = causal ? (blockIdx.x + 1) * 64 : T;  // uniform across waves
  const int ntile = kend >> 6;

  auto stageKV = [&](int tile, int buf) {
    int kv0 = tile << 6;
#pragma unroll
    for (int s = 0; s < 4; ++s) {          // K: 64 rows x 256B, swizzled granules
      int f = s * 4096 + tid * 16;
      int row = f >> 8, g = (f >> 4) & 15;
      int gs = g ^ (row & 7);
      __builtin_amdgcn_global_load_lds(
          (g_void*)(kb + (bT + kv0 + row) * DIM + hc + gs * 8),
          (lds_void*)((char*)&Ks[buf][0] + f), 16, 0, 0);
    }
#pragma unroll
    for (int s = 0; s < 4; ++s) {          // V: 128 rows x 128B, swizzled granules
      int f = s * 4096 + tid * 16;
      int row = f >> 7, g = (f >> 4) & 7;
      int gs = g ^ (row & 7);
      __builtin_amdgcn_global_load_lds(
          (g_void*)(vT + (vrow0 + row) * T + kv0 + gs * 8),
          (lds_void*)((char*)&Vs[buf][0] + f), 16, 0, 0);
    }
  };

  stageKV(0, 0);
  __syncthreads();
  int cur = 0;
  for (int tile = 0; tile < ntile; ++tile) {
    const int kv0 = tile << 6;
    if (tile + 1 < ntile) stageKV(tile + 1, cur ^ 1);
    f32x4 s[4] = {};
#pragma unroll
    for (int ks = 0; ks < 4; ++ks) {
      s16x8 kf[4];
#pragma unroll
      for (int ni = 0; ni < 4; ++ni) {
        int row = ni * 16 + lr;
        int g = (ks * 4 + lg) ^ (row & 7);
        kf[ni] = *(const s16x8*)(&Ks[cur][0] + row * 128 + g * 8);
      }
#pragma unroll
      for (int ni = 0; ni < 4; ++ni)
        s[ni] = __builtin_amdgcn_mfma_f32_16x16x32_bf16(qf[ks], kf[ni], s[ni], 0, 0, 0);
    }
    const bool domask = causal && (kv0 + 63 > q0);
#pragma unroll
    for (int r = 0; r < 4; ++r) {
      const int qrow = q0 + lg * 4 + r;
      float mx = -3e38f;
#pragma unroll
      for (int ni = 0; ni < 4; ++ni) {
        float v = s[ni][r] * 0.08838834764831845f;
        if (domask && (kv0 + ni * 16 + lr > qrow)) v = -3e38f;
        s[ni][r] = v;
        mx = fmaxf(mx, v);
      }
#pragma unroll
      for (int dd = 1; dd < 16; dd <<= 1) mx = fmaxf(mx, __shfl_xor(mx, dd));
      float mn = fmaxf(m[r], mx);
      float alpha = __expf(m[r] - mn);
      m[r] = mn;
      float ps = 0.f;
#pragma unroll
      for (int ni = 0; ni < 4; ++ni) {
        float p = __expf(s[ni][r] - mn);
        s[ni][r] = p;
        ps += p;
      }
#pragma unroll
      for (int dd = 1; dd < 16; dd <<= 1) ps += __shfl_xor(ps, dd);
      lac[r] = lac[r] * alpha + ps;
#pragma unroll
      for (int dni = 0; dni < 8; ++dni) O[dni][r] *= alpha;
      const int qloc = lg * 4 + r;
      const int sw = (qloc & 7) << 3;
#pragma unroll
      for (int ni = 0; ni < 4; ++ni)
        Pst[wq][qloc * 64 + ((ni * 16 + lr) ^ sw)] = f2bf(s[ni][r]);
    }
    asm volatile("s_waitcnt lgkmcnt(0)" ::: "memory");
    __builtin_amdgcn_sched_barrier(0);
#pragma unroll
    for (int ks2 = 0; ks2 < 2; ++ks2) {
      s16x8 pa = *(const s16x8*)&Pst[wq][lr * 64 + ((ks2 * 32 + lg * 8) ^ ((lr & 7) << 3))];
#pragma unroll
      for (int dni = 0; dni < 8; ++dni) {
        int row = dni * 16 + lr;
        int g = (ks2 * 4 + lg) ^ (row & 7);
        s16x8 vf = *(const s16x8*)(&Vs[cur][0] + row * 64 + g * 8);
        O[dni] = __builtin_amdgcn_mfma_f32_16x16x32_bf16(pa, vf, O[dni], 0, 0, 0);
      }
    }
    __syncthreads();   // drains next-tile staging; compute above covered most of it
    cur ^= 1;
  }
#pragma unroll
  for (int r = 0; r < 4; ++r) {
    float inv = 1.f / lac[r];
    const size_t row = bT + q0 + lg * 4 + r;
#pragma unroll
    for (int dni = 0; dni < 8; ++dni)
      outA[row * DIM + hc + dni * 16 + lr] = f2bf(O[dni][r] * inv);
  }
}

// ---------------------------------------------------------------------------
extern "C" void kernel_launch(void* const* d_in, const int* in_sizes, int n_in,
                              void* d_out, int out_size, void* d_ws, size_t ws_size,
                              hipStream_t stream) {
  const int*   src        = (const int*)d_in[0];
  const int*   tgt        = (const int*)d_in[1];
  const float* emb        = (const float*)d_in[3];
  const float* enc_attn_W = (const float*)d_in[4];
  const float* enc_attn_b = (const float*)d_in[5];
  const float* enc_norm_g = (const float*)d_in[6];
  const float* enc_norm_b = (const float*)d_in[7];
  const float* enc_ff_W1  = (const float*)d_in[8];
  const float* enc_ff_b1  = (const float*)d_in[9];
  const float* enc_ff_mod = (const float*)d_in[10];
  const float* enc_ff_W2  = (const float*)d_in[11];
  const float* enc_ff_b2  = (const float*)d_in[12];
  const float* dec_sa_W   = (const float*)d_in[13];
  const float* dec_sa_b   = (const float*)d_in[14];
  const float* dec_ca_W   = (const float*)d_in[15];
  const float* dec_ca_b   = (const float*)d_in[16];
  const float* dec_norm_g = (const float*)d_in[17];
  const float* dec_norm_b = (const float*)d_in[18];
  const float* dec_ff_W1  = (const float*)d_in[19];
  const float* dec_ff_b1  = (const float*)d_in[20];
  const float* dec_ff_mod = (const float*)d_in[21];
  const float* dec_ff_W2  = (const float*)d_in[22];
  const float* dec_ff_b2  = (const float*)d_in[23];
  const float* fc_W       = (const float*)d_in[24];
  const float* fc_b       = (const float*)d_in[25];
  float* out = (float*)d_out;

  const size_t SZX = (size_t)BT * DIM;  // 2,097,152
  float* ws    = (float*)d_ws;
  float* xsrc  = ws;
  float* xtgt  = xsrc + SZX;
  ushort* xbf_src = (ushort*)(xtgt + SZX);
  ushort* xbf_tgt = xbf_src + SZX;
  ushort* aobf    = xbf_tgt + SZX;
  ushort* qb      = aobf + SZX;
  ushort* kb      = qb + SZX;
  ushort* vTb     = kb + SZX;
  ushort* hbf     = vTb + SZX;                    // BT*4096
  ushort* realbf  = hbf + (size_t)BT * H * 4;     // BT*256
  ushort* WA      = realbf + (size_t)BT * D;      // 24 * WSTEP
  ushort* WF      = WA + (size_t)6 * 4 * WSTEP;   // 8 * FFW
  ushort* Wfc     = WF + (size_t)4 * 2 * FFW;     // V*D

  mega_expand_kernel<<<(MEGA_TOT + 255) / 256, 256, 0, stream>>>(
      enc_attn_W, dec_sa_W, dec_ca_W,
      enc_ff_W1, enc_ff_W2, dec_ff_W1, dec_ff_W2, fc_W, WA, WF, Wfc);

  auto g_qkv = [&](const ushort* Ab, const ushort* Btw, const float* bias,
                   int N, int colbase, bool tm64) {
    if (tm64)
      gemm_bf16_kernel<3, 64><<<(N / 128) * (BT / 64), 256, 0, stream>>>(
          Ab, Btw, bias, nullptr, N, DIM, qb, kb, vTb, colbase,
          nullptr, nullptr, nullptr, nullptr, nullptr, nullptr);
    else
      gemm_bf16_kernel<3, 128><<<(N / 128) * (BT / 128), 256, 0, stream>>>(
          Ab, Btw, bias, nullptr, N, DIM, qb, kb, vTb, colbase,
          nullptr, nullptr, nullptr, nullptr, nullptr, nullptr);
  };
  auto g_qnorm = [&](const ushort* Ab, const ushort* Btw, const float* bias,
                     int K, float* xres, ushort* xbf, const float* ngv,
                     const float* nbv, ushort* realo) {
    gemm_bf16_kernel<4, 64><<<(DIM / 128) * (BT / 64), 256, 0, stream>>>(
        Ab, Btw, bias, nullptr, DIM, K, nullptr, nullptr, nullptr, 0,
        xres, xbf, ngv, nbv, nullptr, realo);
  };
  auto g_modrelu = [&](const ushort* Ab, const ushort* Btw, const float* b1,
                       const float* mod) {
    gemm_bf16_kernel<5, 128><<<(4 * H / 128) * (BT / 128), 256, 0, stream>>>(
        Ab, Btw, b1, hbf, 4 * H, DIM, nullptr, nullptr, nullptr, 0,
        nullptr, nullptr, nullptr, nullptr, mod, nullptr);
  };

  // unit: 0,1 enc; 2,3 dec_sa; 4,5 dec_ca
  auto attention = [&](const ushort* qbf_in, const ushort* kvbf_in, int unit,
                       const float* bbp, int causal, float* xres, ushort* xbf,
                       const float* ngv, const float* nbv) {
    const ushort* Wu = WA + (size_t)unit * 4 * WSTEP;
    if (qbf_in == kvbf_in) {
      g_qkv(qbf_in, Wu, bbp, 3 * DIM, 0, false);
    } else {
      g_qkv(qbf_in, Wu, bbp, DIM, 0, true);
      g_qkv(kvbf_in, Wu + WSTEP, bbp, 2 * DIM, DIM, false);
    }
    fused_attn_kernel<<<dim3(T / 64, NH, B), 256, 0, stream>>>(qb, kb, vTb, aobf, causal);
    g_qnorm(aobf, Wu + 3 * WSTEP, bbp + 3 * DIM, DIM, xres, xbf, ngv, nbv, nullptr);
  };

  auto ff = [&](const ushort* xbf_in, int layer, const float* b1, const float* mod,
                const float* b2, float* xres, ushort* xbf, const float* ngv,
                const float* nbv, ushort* realo) {
    const ushort* Wf = WF + (size_t)layer * 2 * FFW;
    g_modrelu(xbf_in, Wf, b1, mod);
    g_qnorm(hbf, Wf + FFW, b2, 4 * H, xres, xbf, ngv, nbv, realo);
  };

  embed_rope_kernel<<<2 * BT, 256, 0, stream>>>(src, tgt, emb, xsrc, xbf_src,
                                                xtgt, xbf_tgt);

  for (int l = 0; l < LE; ++l) {
    attention(xbf_src, xbf_src, l, enc_attn_b + (size_t)l * 4 * DIM, 0,
              xsrc, xbf_src,
              enc_norm_g + (size_t)(l * 2 + 0) * DIM,
              enc_norm_b + (size_t)(l * 2 + 0) * DIM);
    ff(xbf_src, l, enc_ff_b1 + (size_t)l * H * 4, enc_ff_mod + (size_t)l * H,
       enc_ff_b2 + (size_t)l * DIM, xsrc, xbf_src,
       enc_norm_g + (size_t)(l * 2 + 1) * DIM,
       enc_norm_b + (size_t)(l * 2 + 1) * DIM, nullptr);
  }

  for (int l = 0; l < LD; ++l) {
    attention(xbf_tgt, xbf_tgt, 2 + l, dec_sa_b + (size_t)l * 4 * DIM, 1,
              xtgt, xbf_tgt,
              dec_norm_g + (size_t)(l * 3 + 0) * DIM,
              dec_norm_b + (size_t)(l * 3 + 0) * DIM);
    attention(xbf_tgt, xbf_src, 4 + l, dec_ca_b + (size_t)l * 4 * DIM, 0,
              xtgt, xbf_tgt,
              dec_norm_g + (size_t)(l * 3 + 1) * DIM,
              dec_norm_b + (size_t)(l * 3 + 1) * DIM);
    ff(xbf_tgt, 2 + l, dec_ff_b1 + (size_t)l * H * 4, dec_ff_mod + (size_t)l * H,
       dec_ff_b2 + (size_t)l * DIM, xtgt, xbf_tgt,
       dec_norm_g + (size_t)(l * 3 + 2) * DIM,
       dec_norm_b + (size_t)(l * 3 + 2) * DIM,
       (l == LD - 1) ? realbf : nullptr);
  }

  gemm_bf16_kernel<0, 128><<<(V / 128) * (BT / 128), 256, 0, stream>>>(
      realbf, Wfc, fc_b, out, V, 256, nullptr, nullptr, nullptr, 0,
      nullptr, nullptr, nullptr, nullptr, nullptr, nullptr);
}

// Round 9
// 1120.105 us; speedup vs baseline: 1.1327x; 1.1327x over previous
//
#include <hip/hip_runtime.h>
#include <math.h>

#define B 4
#define T 512
#define D 256
#define H 1024
#define NH 8
#define V 32000
#define BT (B*T)
#define LE 2
#define LD 2
#define DIM 1024  // expanded width = 4*D

typedef __attribute__((ext_vector_type(8))) short s16x8;
typedef __attribute__((ext_vector_type(4))) float f32x4;
typedef __attribute__((address_space(3))) void lds_void;
typedef const __attribute__((address_space(1))) void g_void;

__device__ __forceinline__ ushort f2bf(float x) {
  uint u = __float_as_uint(x);
  return (ushort)((u + 0x7fffu + ((u >> 16) & 1u)) >> 16);
}

// ---------------------------------------------------------------------------
// embed + rope fused for BOTH src and tgt: grid 2*BT
__global__ __launch_bounds__(256) void embed_rope_kernel(
    const int* __restrict__ src, const int* __restrict__ tgt,
    const float* __restrict__ emb,
    float* __restrict__ osrc, ushort* __restrict__ osrcbf,
    float* __restrict__ otgt, ushort* __restrict__ otgtbf) {
  int g = blockIdx.x;
  int isTgt = g >= BT;
  int bt = isTgt ? g - BT : g;
  int d  = threadIdx.x;
  int id = isTgt ? tgt[bt] : src[bt];
  float* out = isTgt ? otgt : osrc;
  ushort* outbf = isTgt ? otgtbf : osrcbf;
  int t  = bt % T;
  size_t VD = (size_t)V * D;
  float scale = powf(10000.f, -(float)d / (float)D);
  float r = emb[(size_t)id * D + d];
  float i = emb[VD + (size_t)id * D + d] * scale;
  float j = emb[2 * VD + (size_t)id * D + d] * scale;
  float k = emb[3 * VD + (size_t)id * D + d] * scale;
  float n = sqrtf(r * r + i * i + j * j + k * k + 1e-6f);
  float ang;
  if (d < D / 2) {
    float inv = powf(10000.f, -(float)(2 * d) / (float)D);
    ang = sinf((float)t * inv);
  } else {
    float inv = powf(10000.f, -(float)(2 * (d - D / 2)) / (float)D);
    ang = cosf((float)t * inv);
  }
  float s = ang / n;
  size_t base = (size_t)bt * DIM + d * 4;
  float4 q = make_float4(r * s, i * s, j * s, k * s);
  *(float4*)(out + base) = q;
  *(ushort4*)(outbf + base) = make_ushort4(f2bf(q.x), f2bf(q.y), f2bf(q.z), f2bf(q.w));
}

// ---------------------------------------------------------------------------
// ONE launch: expand all quaternion weights to bf16 B^T form + fc_W convert
#define A_CNT  1572864
#define F_CNT  2097152
#define FC_CNT 2048000
#define MEGA_TOT (A_CNT + F_CNT + FC_CNT)
#define WSTEP  1048576   // DIM*DIM elems
#define FFW    4194304   // 4H*DIM elems

__device__ __forceinline__ void qexpand_write(
    const float* __restrict__ src, ushort* __restrict__ dst,
    int o, int d, int Din, int P) {
  float w0 = src[(size_t)o * Din + d];
  float w1 = src[P + (size_t)o * Din + d];
  float w2 = src[2 * (size_t)P + (size_t)o * Din + d];
  float w3 = src[3 * (size_t)P + (size_t)o * Din + d];
  int K4 = Din * 4;
  size_t rbase = (size_t)(o * 4) * K4 + d * 4;
  *(ushort4*)(dst + rbase)          = make_ushort4(f2bf(w0), f2bf(-w1), f2bf(-w2), f2bf(-w3));
  *(ushort4*)(dst + rbase + K4)     = make_ushort4(f2bf(w1), f2bf(w0),  f2bf(w3),  f2bf(-w2));
  *(ushort4*)(dst + rbase + 2 * K4) = make_ushort4(f2bf(w2), f2bf(-w3), f2bf(w0),  f2bf(w1));
  *(ushort4*)(dst + rbase + 3 * K4) = make_ushort4(f2bf(w3), f2bf(w2),  f2bf(-w1), f2bf(w0));
}

__global__ __launch_bounds__(256) void mega_expand_kernel(
    const float* __restrict__ encA, const float* __restrict__ decSA,
    const float* __restrict__ decCA,
    const float* __restrict__ eW1, const float* __restrict__ eW2,
    const float* __restrict__ dW1, const float* __restrict__ dW2,
    const float* __restrict__ fcW,
    ushort* __restrict__ WA, ushort* __restrict__ WF, ushort* __restrict__ Wfc) {
  int gid = blockIdx.x * 256 + threadIdx.x;
  if (gid < A_CNT) {
    int u = gid >> 18;
    int p = (gid >> 16) & 3;
    int rem = gid & 65535;
    int o = rem >> 8, d = rem & 255;
    const float* base = (u < 2) ? encA + (size_t)u * 1048576
                      : (u < 4) ? decSA + (size_t)(u - 2) * 1048576
                                : decCA + (size_t)(u - 4) * 1048576;
    qexpand_write(base + (size_t)p * 262144,
                  WA + ((size_t)u * 4 + p) * WSTEP, o, d, 256, 65536);
  } else if (gid < A_CNT + F_CNT) {
    int idx = gid - A_CNT;
    int layer = idx >> 19;
    int w12 = (idx >> 18) & 1;
    int rem = idx & 262143;
    const float* w1b = (layer < 2) ? eW1 + (size_t)layer * 1048576
                                   : dW1 + (size_t)(layer - 2) * 1048576;
    const float* w2b = (layer < 2) ? eW2 + (size_t)layer * 1048576
                                   : dW2 + (size_t)(layer - 2) * 1048576;
    ushort* dst = WF + (size_t)layer * 2 * FFW + (size_t)w12 * FFW;
    if (w12 == 0) {
      int o = rem >> 8, d = rem & 255;
      qexpand_write(w1b, dst, o, d, 256, 262144);
    } else {
      int o = rem >> 10, d = rem & 1023;
      qexpand_write(w2b, dst, o, d, 1024, 262144);
    }
  } else {
    int idx = gid - A_CNT - F_CNT;
    if (idx < FC_CNT) {
      float4 v = ((const float4*)fcW)[idx];
      ((ushort4*)Wfc)[idx] = make_ushort4(f2bf(v.x), f2bf(v.y), f2bf(v.z), f2bf(v.w));
    }
  }
}

// ---------------------------------------------------------------------------
// Unit-routed GEMM. A dispatch can carry 1 or 2 independent GEMM units
// (same M,N,K; different A/B/epilogue targets) — blocks route by index.
// Optional A-split by column panel (Aalt for n0 >= altStart).
struct GP {
  const ushort* A; const ushort* Aalt; int altStart;
  const ushort* Bt; const float* bias; void* Cv;
  ushort* qo; ushort* ko; ushort* vo;
  float* xres; ushort* xbf; const float* gg; const float* bb;
  const float* modb; ushort* realout;
};

// BK=32, 2-buffer LDS (32/24 KB), stage(t+1) before compute(t), one
// barrier/K-step (r4-proven core). __launch_bounds__(256,4): VGPR<=128 ->
// 4 blocks/CU. XCD-bijective remap, m-fastest (B panels L2-resident).
// OMODE 0: f32+bias. OMODE 3: QKV epilogue. OMODE 4: +resid+qnorm (+real).
// OMODE 5: +modrelu -> bf16.
template <int OMODE, int TM>
__global__ __launch_bounds__(256, 4) void gemm_bf16_kernel(
    GP u0, GP u1, int nunits, int N, int K) {
  __shared__ ushort As[2][TM * 32];
  __shared__ ushort Bs[2][128 * 32];
  const int tid = threadIdx.x;
  const int w = tid >> 6, l = tid & 63;
  const int nwg = gridDim.x;
  const int qq = nwg >> 3, rr = nwg & 7;
  const int xcd = blockIdx.x & 7, pos = blockIdx.x >> 3;
  const int wg = (xcd < rr ? xcd * (qq + 1) : rr * (qq + 1) + (xcd - rr) * qq) + pos;
  const int uwg = nwg / nunits;
  const int unit = wg / uwg;
  const int wgl = wg - unit * uwg;
  GP U = unit ? u1 : u0;
  const int nbx = N >> 7;
  const int nby = uwg / nbx;
  const int m0 = (wgl % nby) * TM, n0 = (wgl / nby) * 128;
  const ushort* Ap = (U.altStart && n0 >= U.altStart) ? U.Aalt : U.A;
  const ushort* Btp = U.Bt;
  const int lr = l & 15, lg = l >> 4;
  constexpr int NR = (TM == 128) ? 4 : 2;
  const int wm = (TM == 128) ? (w >> 1) : 0;
  const int wn = (TM == 128) ? (w & 1) : w;
  const int wcol = wn * (NR * 16);
  f32x4 acc[4][NR] = {};
  const int NT = K >> 5;

  auto stage = [&](int t, int buf) {
    int k0 = t << 5;
#pragma unroll
    for (int s = 0; s < TM / 64; ++s) {
      int fb = (w * (TM / 64) + s) * 1024;
      int f = fb + l * 16;
      int row = f >> 6, cb = (f & 63) >> 1;
      __builtin_amdgcn_global_load_lds(
          (g_void*)(Ap + (size_t)(m0 + row) * K + k0 + cb),
          (lds_void*)((char*)&As[buf][0] + fb), 16, 0, 0);
    }
#pragma unroll
    for (int s = 0; s < 2; ++s) {
      int fb = (w * 2 + s) * 1024;
      int f = fb + l * 16;
      int row = f >> 6, cb = (f & 63) >> 1;
      __builtin_amdgcn_global_load_lds(
          (g_void*)(Btp + (size_t)(n0 + row) * K + k0 + cb),
          (lds_void*)((char*)&Bs[buf][0] + fb), 16, 0, 0);
    }
  };

  stage(0, 0);
  __syncthreads();
  int cur = 0;
  for (int t = 0; t < NT; ++t) {
    if (t + 1 < NT) stage(t + 1, cur ^ 1);
    s16x8 af[4], bfr[NR];
#pragma unroll
    for (int mi = 0; mi < 4; ++mi)
      af[mi] = *(const s16x8*)(&As[cur][0] + (wm * 64 + mi * 16 + lr) * 32 + lg * 8);
#pragma unroll
    for (int ni = 0; ni < NR; ++ni)
      bfr[ni] = *(const s16x8*)(&Bs[cur][0] + (wcol + ni * 16 + lr) * 32 + lg * 8);
    __builtin_amdgcn_s_setprio(1);
#pragma unroll
    for (int mi = 0; mi < 4; ++mi)
#pragma unroll
      for (int ni = 0; ni < NR; ++ni)
        acc[mi][ni] = __builtin_amdgcn_mfma_f32_16x16x32_bf16(af[mi], bfr[ni], acc[mi][ni], 0, 0, 0);
    __builtin_amdgcn_s_setprio(0);
    __syncthreads();
    cur ^= 1;
  }

#pragma unroll
  for (int mi = 0; mi < 4; ++mi) {
#pragma unroll
    for (int ni = 0; ni < NR; ++ni) {
      int row = m0 + wm * 64 + mi * 16 + lg * 4;
      int col = n0 + wcol + ni * 16 + lr;
      f32x4 v = acc[mi][ni];
      if constexpr (OMODE == 0) {
        float bv = U.bias ? U.bias[col] : 0.f;
        float* C = (float*)U.Cv;
#pragma unroll
        for (int r = 0; r < 4; ++r)
          C[(size_t)(row + r) * N + col] = v[r] + bv;
      } else if constexpr (OMODE == 3) {
        float bv = U.bias[col];
        if (col < 2048) {
          ushort* dst = (col < DIM) ? U.qo : U.ko;
          int c = col & (DIM - 1);
#pragma unroll
          for (int r = 0; r < 4; ++r)
            dst[(size_t)(row + r) * DIM + c] = f2bf(v[r] + bv);
        } else {
          int c = col - 2048;
          ushort4 o4 = make_ushort4(f2bf(v[0] + bv), f2bf(v[1] + bv),
                                    f2bf(v[2] + bv), f2bf(v[3] + bv));
          *(ushort4*)&U.vo[((size_t)((row >> 9) << 10) + c) * T + (row & 511)] = o4;
        }
      } else if constexpr (OMODE == 4) {
        float bv = U.bias[col];
        float gv = U.gg[col], bev = U.bb[col];
#pragma unroll
        for (int r = 0; r < 4; ++r) {
          float val = v[r] + bv + U.xres[(size_t)(row + r) * DIM + col];
          float sq = val * val;
          sq += __shfl_xor(sq, 1);
          sq += __shfl_xor(sq, 2);
          float invn = rsqrtf(sq + 1e-6f);
          float res = gv * (val * invn) + bev;
          U.xres[(size_t)(row + r) * DIM + col] = res;
          U.xbf[(size_t)(row + r) * DIM + col] = f2bf(res);
          if (U.realout) {
            float rsq = res * res;
            rsq += __shfl_xor(rsq, 1);
            rsq += __shfl_xor(rsq, 2);
            if ((col & 3) == 0)
              U.realout[(size_t)(row + r) * D + (col >> 2)] = f2bf(sqrtf(rsq));
          }
        }
      } else {  // OMODE 5: modrelu
        float bv = U.bias[col];
        float mb = U.modb[col >> 2];
        ushort* C = (ushort*)U.Cv;
#pragma unroll
        for (int r = 0; r < 4; ++r) {
          float val = v[r] + bv;
          float sq = val * val;
          sq += __shfl_xor(sq, 1);
          sq += __shfl_xor(sq, 2);
          float norm = sqrtf(sq);
          float scale = fmaxf(norm + mb, 0.f) / (norm + 1e-6f);
          C[(size_t)(row + r) * N + col] = f2bf(val * scale);
        }
      }
    }
  }
}

// ---------------------------------------------------------------------------
// fused flash attention, head-dim 128. grid (T/64, NH, B*npair), 4 waves.
// z >= B selects unit 1 (buffer offset + its own causal flag).
// K/V staged once/block into XOR-swizzled LDS (dbuf), shared by 4 waves.
__global__ __launch_bounds__(256) void fused_attn_kernel(
    const ushort* __restrict__ qb, const ushort* __restrict__ kb,
    const ushort* __restrict__ vT, ushort* __restrict__ outA,
    int c0, int c1) {
  __shared__ ushort Ks[2][64 * 128];
  __shared__ ushort Vs[2][128 * 64];
  __shared__ ushort Pst[4][1024];
  const int tid = threadIdx.x;
  const int wq = tid >> 6, l = tid & 63;
  const int lr = l & 15, lg = l >> 4;
  const int h = blockIdx.y;
  const int u = blockIdx.z >> 2, b = blockIdx.z & 3;
  const size_t uoff = (size_t)u * ((size_t)BT * DIM);
  const int causal = u ? c1 : c0;
  const int q0 = blockIdx.x * 64 + wq * 16;
  const size_t bT = (size_t)b * T;
  const int hc = h * 128;
  const size_t vrow0 = (size_t)(b * NH + h) * 128;
  const ushort* qbu = qb + uoff;
  const ushort* kbu = kb + uoff;
  const ushort* vTu = vT + uoff;
  ushort* outu = outA + uoff;
  s16x8 qf[4];
#pragma unroll
  for (int ks = 0; ks < 4; ++ks)
    qf[ks] = *(const s16x8*)(qbu + (bT + q0 + lr) * DIM + hc + ks * 32 + lg * 8);
  f32x4 O[8] = {};
  float m[4] = {-3e38f, -3e38f, -3e38f, -3e38f};
  float lac[4] = {0.f, 0.f, 0.f, 0.f};
  const int kend = causal ? (blockIdx.x + 1) * 64 : T;  // uniform across waves
  const int ntile = kend >> 6;

  auto stageKV = [&](int tile, int buf) {
    int kv0 = tile << 6;
#pragma unroll
    for (int s = 0; s < 4; ++s) {          // K: 64 rows x 256B
      int f = s * 4096 + tid * 16;
      int row = f >> 8, g = (f >> 4) & 15;
      int gs = g ^ (row & 7);
      __builtin_amdgcn_global_load_lds(
          (g_void*)(kbu + (bT + kv0 + row) * DIM + hc + gs * 8),
          (lds_void*)((char*)&Ks[buf][0] + f), 16, 0, 0);
    }
#pragma unroll
    for (int s = 0; s < 4; ++s) {          // V: 128 rows x 128B
      int f = s * 4096 + tid * 16;
      int row = f >> 7, g = (f >> 4) & 7;
      int gs = g ^ (row & 7);
      __builtin_amdgcn_global_load_lds(
          (g_void*)(vTu + (vrow0 + row) * T + kv0 + gs * 8),
          (lds_void*)((char*)&Vs[buf][0] + f), 16, 0, 0);
    }
  };

  stageKV(0, 0);
  __syncthreads();
  int cur = 0;
  for (int tile = 0; tile < ntile; ++tile) {
    const int kv0 = tile << 6;
    if (tile + 1 < ntile) stageKV(tile + 1, cur ^ 1);
    f32x4 s[4] = {};
#pragma unroll
    for (int ks = 0; ks < 4; ++ks) {
      s16x8 kf[4];
#pragma unroll
      for (int ni = 0; ni < 4; ++ni) {
        int row = ni * 16 + lr;
        int g = (ks * 4 + lg) ^ (row & 7);
        kf[ni] = *(const s16x8*)(&Ks[cur][0] + row * 128 + g * 8);
      }
#pragma unroll
      for (int ni = 0; ni < 4; ++ni)
        s[ni] = __builtin_amdgcn_mfma_f32_16x16x32_bf16(qf[ks], kf[ni], s[ni], 0, 0, 0);
    }
    const bool domask = causal && (kv0 + 63 > q0);
#pragma unroll
    for (int r = 0; r < 4; ++r) {
      const int qrow = q0 + lg * 4 + r;
      float mx = -3e38f;
#pragma unroll
      for (int ni = 0; ni < 4; ++ni) {
        float v = s[ni][r] * 0.08838834764831845f;
        if (domask && (kv0 + ni * 16 + lr > qrow)) v = -3e38f;
        s[ni][r] = v;
        mx = fmaxf(mx, v);
      }
#pragma unroll
      for (int dd = 1; dd < 16; dd <<= 1) mx = fmaxf(mx, __shfl_xor(mx, dd));
      float mn = fmaxf(m[r], mx);
      float alpha = __expf(m[r] - mn);
      m[r] = mn;
      float ps = 0.f;
#pragma unroll
      for (int ni = 0; ni < 4; ++ni) {
        float p = __expf(s[ni][r] - mn);
        s[ni][r] = p;
        ps += p;
      }
#pragma unroll
      for (int dd = 1; dd < 16; dd <<= 1) ps += __shfl_xor(ps, dd);
      lac[r] = lac[r] * alpha + ps;
#pragma unroll
      for (int dni = 0; dni < 8; ++dni) O[dni][r] *= alpha;
      const int qloc = lg * 4 + r;
      const int sw = (qloc & 7) << 3;
#pragma unroll
      for (int ni = 0; ni < 4; ++ni)
        Pst[wq][qloc * 64 + ((ni * 16 + lr) ^ sw)] = f2bf(s[ni][r]);
    }
    asm volatile("s_waitcnt lgkmcnt(0)" ::: "memory");
    __builtin_amdgcn_sched_barrier(0);
#pragma unroll
    for (int ks2 = 0; ks2 < 2; ++ks2) {
      s16x8 pa = *(const s16x8*)&Pst[wq][lr * 64 + ((ks2 * 32 + lg * 8) ^ ((lr & 7) << 3))];
#pragma unroll
      for (int dni = 0; dni < 8; ++dni) {
        int row = dni * 16 + lr;
        int g = (ks2 * 4 + lg) ^ (row & 7);
        s16x8 vf = *(const s16x8*)(&Vs[cur][0] + row * 64 + g * 8);
        O[dni] = __builtin_amdgcn_mfma_f32_16x16x32_bf16(pa, vf, O[dni], 0, 0, 0);
      }
    }
    __syncthreads();
    cur ^= 1;
  }
#pragma unroll
  for (int r = 0; r < 4; ++r) {
    float inv = 1.f / lac[r];
    const size_t row = bT + q0 + lg * 4 + r;
#pragma unroll
    for (int dni = 0; dni < 8; ++dni)
      outu[row * DIM + hc + dni * 16 + lr] = f2bf(O[dni][r] * inv);
  }
}

// ---------------------------------------------------------------------------
extern "C" void kernel_launch(void* const* d_in, const int* in_sizes, int n_in,
                              void* d_out, int out_size, void* d_ws, size_t ws_size,
                              hipStream_t stream) {
  const int*   src        = (const int*)d_in[0];
  const int*   tgt        = (const int*)d_in[1];
  const float* emb        = (const float*)d_in[3];
  const float* enc_attn_W = (const float*)d_in[4];
  const float* enc_attn_b = (const float*)d_in[5];
  const float* enc_norm_g = (const float*)d_in[6];
  const float* enc_norm_b = (const float*)d_in[7];
  const float* enc_ff_W1  = (const float*)d_in[8];
  const float* enc_ff_b1  = (const float*)d_in[9];
  const float* enc_ff_mod = (const float*)d_in[10];
  const float* enc_ff_W2  = (const float*)d_in[11];
  const float* enc_ff_b2  = (const float*)d_in[12];
  const float* dec_sa_W   = (const float*)d_in[13];
  const float* dec_sa_b   = (const float*)d_in[14];
  const float* dec_ca_W   = (const float*)d_in[15];
  const float* dec_ca_b   = (const float*)d_in[16];
  const float* dec_norm_g = (const float*)d_in[17];
  const float* dec_norm_b = (const float*)d_in[18];
  const float* dec_ff_W1  = (const float*)d_in[19];
  const float* dec_ff_b1  = (const float*)d_in[20];
  const float* dec_ff_mod = (const float*)d_in[21];
  const float* dec_ff_W2  = (const float*)d_in[22];
  const float* dec_ff_b2  = (const float*)d_in[23];
  const float* fc_W       = (const float*)d_in[24];
  const float* fc_b       = (const float*)d_in[25];
  float* out = (float*)d_out;

  const size_t USZ = (size_t)BT * DIM;  // 2,097,152 per unit
  float* ws    = (float*)d_ws;
  float* xsrc  = ws;
  float* xtgt  = xsrc + USZ;
  ushort* xbf_src = (ushort*)(xtgt + USZ);
  ushort* xbf_tgt = xbf_src + USZ;
  ushort* aobf    = xbf_tgt + USZ;      // 2 units
  ushort* qb      = aobf + 2 * USZ;     // 2 units
  ushort* kb      = qb + 2 * USZ;       // 2 units
  ushort* vTb     = kb + 2 * USZ;       // 2 units
  ushort* hbf     = vTb + 2 * USZ;      // BT*4096
  ushort* realbf  = hbf + (size_t)BT * H * 4;
  ushort* WA      = realbf + (size_t)BT * D;      // 24 * WSTEP
  ushort* WF      = WA + (size_t)6 * 4 * WSTEP;   // 8 * FFW
  ushort* Wfc     = WF + (size_t)4 * 2 * FFW;     // V*D

  mega_expand_kernel<<<(MEGA_TOT + 255) / 256, 256, 0, stream>>>(
      enc_attn_W, dec_sa_W, dec_ca_W,
      enc_ff_W1, enc_ff_W2, dec_ff_W1, dec_ff_W2, fc_W, WA, WF, Wfc);

  embed_rope_kernel<<<2 * BT, 256, 0, stream>>>(src, tgt, emb, xsrc, xbf_src,
                                                xtgt, xbf_tgt);

  GP Z{};  // zero template

  // QKV: OMODE3, TM=128, N=3072, K=1024, 384 blocks/unit
  auto mkQKV = [&](const ushort* Abf, const ushort* Wu, const float* bb, int u) {
    GP g = Z;
    g.A = Abf; g.Bt = Wu; g.bias = bb;
    g.qo = qb + u * USZ; g.ko = kb + u * USZ; g.vo = vTb + u * USZ;
    return g;
  };
  // OP: OMODE4, TM=64, N=1024, K=1024, 256 blocks/unit
  auto mkOP = [&](int u, const ushort* Wu3, const float* bb, float* xres,
                  ushort* xbf, const float* gg, const float* nb, ushort* realo) {
    GP g = Z;
    g.A = aobf + u * USZ; g.Bt = Wu3; g.bias = bb;
    g.xres = xres; g.xbf = xbf; g.gg = gg; g.bb = nb; g.realout = realo;
    return g;
  };

  auto qkv1 = [&](GP g) {
    gemm_bf16_kernel<3, 128><<<384, 256, 0, stream>>>(g, g, 1, 3 * DIM, DIM);
  };
  auto qkv2 = [&](GP g0, GP g1) {
    gemm_bf16_kernel<3, 128><<<768, 256, 0, stream>>>(g0, g1, 2, 3 * DIM, DIM);
  };
  auto op1 = [&](GP g) {
    gemm_bf16_kernel<4, 64><<<256, 256, 0, stream>>>(g, g, 1, DIM, DIM);
  };
  auto op2 = [&](GP g0, GP g1) {
    gemm_bf16_kernel<4, 64><<<512, 256, 0, stream>>>(g0, g1, 2, DIM, DIM);
  };
  auto attn1 = [&](int causal) {
    fused_attn_kernel<<<dim3(T / 64, NH, B), 256, 0, stream>>>(
        qb, kb, vTb, aobf, causal, causal);
  };
  auto ffpair = [&](const ushort* xbf, int layer, const float* b1,
                    const float* mod, const float* b2, float* xres,
                    ushort* xbfo, const float* gg, const float* nb,
                    ushort* realo) {
    const ushort* Wf = WF + (size_t)layer * 2 * FFW;
    GP g1 = Z;
    g1.A = xbf; g1.Bt = Wf; g1.bias = b1; g1.Cv = hbf; g1.modb = mod;
    gemm_bf16_kernel<5, 128><<<512, 256, 0, stream>>>(g1, g1, 1, 4 * H, DIM);
    GP g2 = Z;
    g2.A = hbf; g2.Bt = Wf + FFW; g2.bias = b2;
    g2.xres = xres; g2.xbf = xbfo; g2.gg = gg; g2.bb = nb; g2.realout = realo;
    gemm_bf16_kernel<4, 64><<<256, 256, 0, stream>>>(g2, g2, 1, DIM, 4 * H);
  };

  // ---- enc.l0 ∥ dec.sa0 (independent) : merged QKV / attn / out-proj
  {
    GP e = mkQKV(xbf_src, WA + (size_t)(0 * 4) * WSTEP, enc_attn_b, 0);
    GP d = mkQKV(xbf_tgt, WA + (size_t)(2 * 4) * WSTEP, dec_sa_b, 1);
    qkv2(e, d);
    fused_attn_kernel<<<dim3(T / 64, NH, 2 * B), 256, 0, stream>>>(
        qb, kb, vTb, aobf, 0, 1);
    GP eo = mkOP(0, WA + (size_t)(0 * 4 + 3) * WSTEP, enc_attn_b + 3 * DIM,
                 xsrc, xbf_src, enc_norm_g, enc_norm_b, nullptr);
    GP dо = mkOP(1, WA + (size_t)(2 * 4 + 3) * WSTEP, dec_sa_b + 3 * DIM,
                 xtgt, xbf_tgt, dec_norm_g, dec_norm_b, nullptr);
    op2(eo, dо);
  }
  // enc.l0 FF
  ffpair(xbf_src, 0, enc_ff_b1, enc_ff_mod, enc_ff_b2, xsrc, xbf_src,
         enc_norm_g + 1 * DIM, enc_norm_b + 1 * DIM, nullptr);
  // ---- enc.l1 full layer
  {
    GP e = mkQKV(xbf_src, WA + (size_t)(1 * 4) * WSTEP,
                 enc_attn_b + (size_t)1 * 4 * DIM, 0);
    qkv1(e);
    attn1(0);
    GP eo = mkOP(0, WA + (size_t)(1 * 4 + 3) * WSTEP,
                 enc_attn_b + (size_t)1 * 4 * DIM + 3 * DIM,
                 xsrc, xbf_src, enc_norm_g + 2 * DIM, enc_norm_b + 2 * DIM, nullptr);
    op1(eo);
  }
  ffpair(xbf_src, 1, enc_ff_b1 + (size_t)1 * H * 4, enc_ff_mod + H,
         enc_ff_b2 + DIM, xsrc, xbf_src,
         enc_norm_g + 3 * DIM, enc_norm_b + 3 * DIM, nullptr);

  // ---- decoder layers (SA for l=1 only; l=0 SA already done above)
  for (int l = 0; l < LD; ++l) {
    if (l > 0) {
      GP d = mkQKV(xbf_tgt, WA + (size_t)((2 + l) * 4) * WSTEP,
                   dec_sa_b + (size_t)l * 4 * DIM, 0);
      qkv1(d);
      attn1(1);
      GP od = mkOP(0, WA + (size_t)((2 + l) * 4 + 3) * WSTEP,
                   dec_sa_b + (size_t)l * 4 * DIM + 3 * DIM,
                   xtgt, xbf_tgt, dec_norm_g + (size_t)(l * 3) * DIM,
                   dec_norm_b + (size_t)(l * 3) * DIM, nullptr);
      op1(od);
    }
    // cross-attention: Q from xtgt, K/V from xsrc — one merged-A QKV dispatch
    {
      GP g = mkQKV(xbf_tgt, WA + (size_t)((4 + l) * 4) * WSTEP,
                   dec_ca_b + (size_t)l * 4 * DIM, 0);
      g.Aalt = xbf_src; g.altStart = DIM;
      qkv1(g);
      attn1(0);
      GP og = mkOP(0, WA + (size_t)((4 + l) * 4 + 3) * WSTEP,
                   dec_ca_b + (size_t)l * 4 * DIM + 3 * DIM,
                   xtgt, xbf_tgt, dec_norm_g + (size_t)(l * 3 + 1) * DIM,
                   dec_norm_b + (size_t)(l * 3 + 1) * DIM, nullptr);
      op1(og);
    }
    ffpair(xbf_tgt, 2 + l, dec_ff_b1 + (size_t)l * H * 4,
           dec_ff_mod + (size_t)l * H, dec_ff_b2 + (size_t)l * DIM,
           xtgt, xbf_tgt, dec_norm_g + (size_t)(l * 3 + 2) * DIM,
           dec_norm_b + (size_t)(l * 3 + 2) * DIM,
           (l == LD - 1) ? realbf : nullptr);
  }

  // logits
  {
    GP g = Z;
    g.A = realbf; g.Bt = Wfc; g.bias = fc_b; g.Cv = out;
    gemm_bf16_kernel<0, 128><<<(V / 128) * (BT / 128), 256, 0, stream>>>(
        g, g, 1, V, 256);
  }
}